// Round 1
// baseline (206.121 us; speedup 1.0000x reference)
//
#include <hip/hip_runtime.h>

#define IH 640
#define IW 640
#define CROPSZ 512
#define NGRID 8
#define TILE 64          // CROPSZ / NGRID
#define NBINS 256
#define TP (TILE*TILE)   // 4096 pixels per tile
// clip_val = max(0.8 * 4096 / 256, 1.0) = 12.8
#define CLIPV 12.8f

// ---------------------------------------------------------------------------
// Kernel 1: per-(batch,tile) histogram -> clipped/redistributed -> cumsum LUT
// One block of 256 threads per tile. 64 batches * 64 tiles = 4096 blocks.
// ---------------------------------------------------------------------------
__global__ __launch_bounds__(256) void clahe_lut_kernel(
    const float* __restrict__ x,
    const int* __restrict__ hflip, const int* __restrict__ vflip,
    const int* __restrict__ offy,  const int* __restrict__ offx,
    const int* __restrict__ apply,
    float* __restrict__ luts)
{
    const int bt = blockIdx.x;         // b*64 + tile
    const int b  = bt >> 6;
    if (!apply[b]) return;             // block-uniform: LUT never read for these
    const int tile = bt & 63;
    const int tyi = tile >> 3, txi = tile & 7;
    const int hf = hflip[b], vf = vflip[b];
    const int oy = offy[b],  ox = offx[b];

    __shared__ unsigned int hist[NBINS];
    const int t = threadIdx.x;
    hist[t] = 0u;
    __syncthreads();

    const float* __restrict__ xb = x + (size_t)b * (IH * IW);
    const int base_y = tyi * TILE, base_x = txi * TILE;

    #pragma unroll
    for (int k = 0; k < TP / 256; ++k) {
        const int p  = t + k * 256;
        const int cy = base_y + (p >> 6);    // crop-space row
        const int cx = base_x + (p & 63);    // crop-space col
        int iy = oy + cy; if (vf) iy = IH - 1 - iy;
        int ix = ox + cx; if (hf) ix = IW - 1 - ix;
        const float v = xb[iy * IW + ix];
        int bin = (int)(v * 256.0f);
        bin = bin < 0 ? 0 : (bin > 255 ? 255 : bin);
        atomicAdd(&hist[bin], 1u);
    }
    __syncthreads();

    // clip + excess redistribution (one bin per thread)
    const float h       = (float)hist[t];
    const float clipped = fminf(h, CLIPV);
    float ex            = h - clipped;

    const int lane = t & 63;
    const int wid  = t >> 6;

    // wave(64) reduce of excess, then cross-wave via LDS
    #pragma unroll
    for (int off = 32; off > 0; off >>= 1) ex += __shfl_down(ex, off, 64);
    __shared__ float wsum[4];
    if (lane == 0) wsum[wid] = ex;
    __syncthreads();
    const float excess = wsum[0] + wsum[1] + wsum[2] + wsum[3];

    const float hv = clipped + excess * (1.0f / (float)NBINS);

    // 256-wide inclusive scan: wave shfl_up scan + cross-wave prefix
    float s = hv;
    #pragma unroll
    for (int off = 1; off < 64; off <<= 1) {
        const float n = __shfl_up(s, off, 64);
        if (lane >= off) s += n;
    }
    __shared__ float wtot[4];
    if (lane == 63) wtot[wid] = s;
    __syncthreads();
    float prefix = 0.0f;
    for (int w = 0; w < wid; ++w) prefix += wtot[w];
    s += prefix;

    float lut = s * (255.0f / (float)TP);
    lut = fminf(fmaxf(lut, 0.0f), 255.0f);
    luts[(size_t)bt * NBINS + t] = lut;
}

// ---------------------------------------------------------------------------
// Kernel 2: output. 4 consecutive output pixels per thread (float4 store).
// 512*128 = 65536 float4 per batch = 256 blocks per batch -> apply-branch is
// block-uniform. 64*256 = 16384 blocks.
// ---------------------------------------------------------------------------
__global__ __launch_bounds__(256) void augment_out_kernel(
    const float* __restrict__ x,
    const int* __restrict__ hflip, const int* __restrict__ vflip,
    const int* __restrict__ offy,  const int* __restrict__ offx,
    const int* __restrict__ apply,
    const float* __restrict__ luts,
    float* __restrict__ out)
{
    const int idx4 = blockIdx.x * 256 + threadIdx.x;
    const int b    = idx4 >> 16;          // 65536 float4 per batch
    const int rem  = idx4 & 65535;
    const int y    = rem >> 7;            // output row
    const int x4   = (rem & 127) << 2;    // first of 4 output cols

    const int hf = hflip[b], vf = vflip[b];
    const int oy = offy[b],  ox = offx[b];
    const int ap = apply[b];

    const float* __restrict__ xb = x + (size_t)b * (IH * IW);
    int iy = oy + y; if (vf) iy = IH - 1 - iy;
    const float* __restrict__ row = xb + (size_t)iy * IW;

    float v[4];
    #pragma unroll
    for (int j = 0; j < 4; ++j) {
        int ix = ox + x4 + j; if (hf) ix = IW - 1 - ix;
        v[j] = row[ix];
    }

    float4 o;
    if (ap) {
        // vertical interpolation params (shared by the 4 pixels)
        const float tyf = (y + 0.5f) * (1.0f / TILE) - 0.5f;
        const float y0f = floorf(tyf);
        const float fy  = tyf - y0f;
        const int   y0  = max(0, min(NGRID - 1, (int)y0f));
        const int   y1  = max(0, min(NGRID - 1, (int)y0f + 1));
        const float* __restrict__ lb = luts + (size_t)b * (64 * NBINS);

        float r[4];
        #pragma unroll
        for (int j = 0; j < 4; ++j) {
            const int xx = x4 + j;
            const float txf = (xx + 0.5f) * (1.0f / TILE) - 0.5f;
            const float x0f = floorf(txf);
            const float fx  = txf - x0f;
            const int   x0  = max(0, min(NGRID - 1, (int)x0f));
            const int   x1  = max(0, min(NGRID - 1, (int)x0f + 1));

            int bin = (int)(v[j] * 256.0f);
            bin = bin < 0 ? 0 : (bin > 255 ? 255 : bin);

            const float v00 = lb[((y0 << 3) + x0) * NBINS + bin];
            const float v01 = lb[((y0 << 3) + x1) * NBINS + bin];
            const float v10 = lb[((y1 << 3) + x0) * NBINS + bin];
            const float v11 = lb[((y1 << 3) + x1) * NBINS + bin];

            const float top = (1.0f - fx) * v00 + fx * v01;
            const float bot = (1.0f - fx) * v10 + fx * v11;
            r[j] = ((1.0f - fy) * top + fy * bot) / 255.0f;
        }
        o = make_float4(r[0], r[1], r[2], r[3]);
    } else {
        o = make_float4(v[0], v[1], v[2], v[3]);
    }
    reinterpret_cast<float4*>(out)[idx4] = o;
}

// ---------------------------------------------------------------------------
extern "C" void kernel_launch(void* const* d_in, const int* in_sizes, int n_in,
                              void* d_out, int out_size, void* d_ws, size_t ws_size,
                              hipStream_t stream) {
    const float* x     = (const float*)d_in[0];
    const int*   hflip = (const int*)d_in[1];
    const int*   vflip = (const int*)d_in[2];
    const int*   offy  = (const int*)d_in[3];
    const int*   offx  = (const int*)d_in[4];
    const int*   apply = (const int*)d_in[5];
    float*       out   = (float*)d_out;
    float*       luts  = (float*)d_ws;   // 64 batches * 64 tiles * 256 bins * 4B = 4 MiB

    // Kernel 1: LUT build (4096 blocks = 64 batches * 64 tiles)
    hipLaunchKernelGGL(clahe_lut_kernel, dim3(64 * 64), dim3(256), 0, stream,
                       x, hflip, vflip, offy, offx, apply, luts);

    // Kernel 2: output (64 MiB of float4 stores)
    const int nthreads4 = 64 * CROPSZ * CROPSZ / 4;     // 4,194,304
    hipLaunchKernelGGL(augment_out_kernel, dim3(nthreads4 / 256), dim3(256), 0, stream,
                       x, hflip, vflip, offy, offx, apply, luts, out);
}

// Round 3
// 193.705 us; speedup vs baseline: 1.0641x; 1.0641x over previous
//
#include <hip/hip_runtime.h>

#define IH 640
#define IW 640
#define CROPSZ 512
#define NGRID 8
#define TILE 64          // CROPSZ / NGRID
#define NBINS 256
#define TP (TILE*TILE)   // 4096 pixels per tile
// clip_val = max(0.8 * 4096 / 256, 1.0) = 12.8
#define CLIPV 12.8f

typedef float fvec4 __attribute__((ext_vector_type(4)));   // native vector: OK for
                                                           // nontemporal builtins

// ---------------------------------------------------------------------------
// Kernel 1: per-(batch,tile) histogram -> clip/redistribute -> cumsum LUT.
// A histogram is order-independent and flips map the tile onto a mirrored
// contiguous block in input space -> read a plain 64x64 block forward with
// vec4 loads, no per-pixel flip math. One 256-thread block per (batch,tile).
// ---------------------------------------------------------------------------
__global__ __launch_bounds__(256) void clahe_lut_kernel(
    const float* __restrict__ x,
    const int* __restrict__ hflip, const int* __restrict__ vflip,
    const int* __restrict__ offy,  const int* __restrict__ offx,
    const int* __restrict__ apply,
    float* __restrict__ luts)
{
    const int bt = blockIdx.x;         // b*64 + tile  (scalar)
    const int b  = bt >> 6;
    if (!apply[b]) return;             // wave-uniform; LUT never read for these
    const int tile = bt & 63;
    const int tyi = tile >> 3, txi = tile & 7;

    // input-space top-left of the source block (set-equivalent under flips)
    const int oy = offy[b], ox = offx[b];
    const int by = tyi * TILE, bx = txi * TILE;
    const int sy = vflip[b] ? (IH - TILE - oy - by) : (oy + by);
    const int sx = hflip[b] ? (IW - TILE - ox - bx) : (ox + bx);

    __shared__ unsigned int hist[4][NBINS];   // per-wave sub-histograms
    const int t    = threadIdx.x;
    const int lane = t & 63;
    const int wid  = t >> 6;
    #pragma unroll
    for (int w = 0; w < 4; ++w) hist[w][t] = 0u;
    __syncthreads();

    const float* __restrict__ xb = x + (size_t)b * (IH * IW);

    // 64x64 px = 1024 vec4; 256 threads x 4 iters. 16 vec4 per row.
    #pragma unroll
    for (int k = 0; k < 4; ++k) {
        const int q    = t + k * 256;
        const int row  = q >> 4;
        const int col4 = (q & 15) << 2;
        const fvec4 v = *reinterpret_cast<const fvec4*>(
                             xb + (size_t)(sy + row) * IW + sx + col4);
        #pragma unroll
        for (int j = 0; j < 4; ++j) {
            int bin = (int)(v[j] * 256.0f);
            bin = bin < 0 ? 0 : (bin > 255 ? 255 : bin);
            atomicAdd(&hist[wid][bin], 1u);
        }
    }
    __syncthreads();

    // merge sub-histograms, clip, redistribute excess (one bin per thread)
    const float h = (float)(hist[0][t] + hist[1][t] + hist[2][t] + hist[3][t]);
    const float clipped = fminf(h, CLIPV);
    float ex = h - clipped;

    #pragma unroll
    for (int off = 32; off > 0; off >>= 1) ex += __shfl_down(ex, off, 64);
    __shared__ float wsum[4];
    if (lane == 0) wsum[wid] = ex;
    __syncthreads();
    const float excess = wsum[0] + wsum[1] + wsum[2] + wsum[3];

    const float hv = clipped + excess * (1.0f / (float)NBINS);

    // 256-wide inclusive scan: wave shfl_up scan + cross-wave prefix
    float s = hv;
    #pragma unroll
    for (int off = 1; off < 64; off <<= 1) {
        const float n = __shfl_up(s, off, 64);
        if (lane >= off) s += n;
    }
    __shared__ float wtot[4];
    if (lane == 63) wtot[wid] = s;
    __syncthreads();
    float prefix = 0.0f;
    for (int w = 0; w < wid; ++w) prefix += wtot[w];
    s += prefix;

    float lut = s * (255.0f / (float)TP);
    lut = fminf(fmaxf(lut, 0.0f), 255.0f);
    luts[(size_t)bt * NBINS + t] = lut;
}

// ---------------------------------------------------------------------------
// Kernel 2: output. 4 consecutive output pixels per thread, vec4 in/out.
// b derived from blockIdx only -> per-batch params are SGPR, apply-branch is
// wave-uniform. 256 blocks per batch, 16384 blocks total.
// ---------------------------------------------------------------------------
__global__ __launch_bounds__(256) void augment_out_kernel(
    const float* __restrict__ x,
    const int* __restrict__ hflip, const int* __restrict__ vflip,
    const int* __restrict__ offy,  const int* __restrict__ offx,
    const int* __restrict__ apply,
    const float* __restrict__ luts,
    float* __restrict__ out)
{
    const int bid = blockIdx.x;
    const int b   = bid >> 8;             // 256 blocks / batch  (scalar)
    const int t   = threadIdx.x;
    const int q   = ((bid & 255) << 8) + t;   // vec4 index within batch
    const int y   = q >> 7;               // output row (128 vec4 per row)
    const int x4  = (q & 127) << 2;       // first of 4 output cols

    const int hf = hflip[b], vf = vflip[b];
    const int oy = offy[b],  ox = offx[b];
    const int ap = apply[b];

    const int iy = vf ? (IH - 1 - oy - y) : (oy + y);
    const float* __restrict__ row = x + (size_t)b * (IH * IW) + (size_t)iy * IW;

    fvec4 v;
    if (hf) {
        // pixel j maps to col IW-1-ox-x4-j : load mirrored quad, reverse
        const fvec4 r = *reinterpret_cast<const fvec4*>(row + (IW - 4 - ox - x4));
        v = (fvec4){r.w, r.z, r.y, r.x};
    } else {
        v = *reinterpret_cast<const fvec4*>(row + ox + x4);
    }

    fvec4 o;
    if (ap) {
        const float tyf = (y + 0.5f) * (1.0f / TILE) - 0.5f;
        const float y0f = floorf(tyf);
        const float fy  = tyf - y0f;
        const int   y0  = max(0, min(NGRID - 1, (int)y0f));
        const int   y1  = max(0, min(NGRID - 1, (int)y0f + 1));
        const float* __restrict__ lb = luts + (size_t)b * (64 * NBINS);

        #pragma unroll
        for (int j = 0; j < 4; ++j) {
            const int xx = x4 + j;
            const float txf = (xx + 0.5f) * (1.0f / TILE) - 0.5f;
            const float x0f = floorf(txf);
            const float fx  = txf - x0f;
            const int   x0  = max(0, min(NGRID - 1, (int)x0f));
            const int   x1  = max(0, min(NGRID - 1, (int)x0f + 1));

            int bin = (int)(v[j] * 256.0f);
            bin = bin < 0 ? 0 : (bin > 255 ? 255 : bin);

            const float v00 = lb[((y0 << 3) + x0) * NBINS + bin];
            const float v01 = lb[((y0 << 3) + x1) * NBINS + bin];
            const float v10 = lb[((y1 << 3) + x0) * NBINS + bin];
            const float v11 = lb[((y1 << 3) + x1) * NBINS + bin];

            const float top = (1.0f - fx) * v00 + fx * v01;
            const float bot = (1.0f - fx) * v10 + fx * v11;
            o[j] = ((1.0f - fy) * top + fy * bot) * (1.0f / 255.0f);
        }
    } else {
        o = v;
    }
    __builtin_nontemporal_store(o, reinterpret_cast<fvec4*>(out) + ((size_t)bid * 256 + t));
}

// ---------------------------------------------------------------------------
extern "C" void kernel_launch(void* const* d_in, const int* in_sizes, int n_in,
                              void* d_out, int out_size, void* d_ws, size_t ws_size,
                              hipStream_t stream) {
    const float* x     = (const float*)d_in[0];
    const int*   hflip = (const int*)d_in[1];
    const int*   vflip = (const int*)d_in[2];
    const int*   offy  = (const int*)d_in[3];
    const int*   offx  = (const int*)d_in[4];
    const int*   apply = (const int*)d_in[5];
    float*       out   = (float*)d_out;
    float*       luts  = (float*)d_ws;   // 64*64*256*4 B = 4 MiB

    hipLaunchKernelGGL(clahe_lut_kernel, dim3(64 * 64), dim3(256), 0, stream,
                       x, hflip, vflip, offy, offx, apply, luts);

    const int nblocks = 64 * (CROPSZ * CROPSZ / 4) / 256;   // 16384
    hipLaunchKernelGGL(augment_out_kernel, dim3(nblocks), dim3(256), 0, stream,
                       x, hflip, vflip, offy, offx, apply, luts, out);
}

// Round 4
// 181.400 us; speedup vs baseline: 1.1363x; 1.0678x over previous
//
#include <hip/hip_runtime.h>

#define IH 640
#define IW 640
#define CROPSZ 512
#define NGRID 8
#define TILE 64          // CROPSZ / NGRID
#define NBINS 256
#define TP (TILE*TILE)   // 4096 pixels per tile
// clip_val = max(0.8 * 4096 / 256, 1.0) = 12.8
#define CLIPV 12.8f

typedef float fvec4 __attribute__((ext_vector_type(4)));

// ---------------------------------------------------------------------------
// Kernel 1: per-(batch,tile) histogram -> clip/redistribute -> cumsum LUT.
// Histogram is order-independent; flips map the tile onto a mirrored
// contiguous block in input space -> plain forward 64x64 block, vec4 loads.
// One 256-thread block per (batch,tile). 4096 blocks.
// ---------------------------------------------------------------------------
__global__ __launch_bounds__(256) void clahe_lut_kernel(
    const float* __restrict__ x,
    const int* __restrict__ hflip, const int* __restrict__ vflip,
    const int* __restrict__ offy,  const int* __restrict__ offx,
    const int* __restrict__ apply,
    float* __restrict__ luts)
{
    const int bt = blockIdx.x;         // b*64 + tile  (scalar)
    const int b  = bt >> 6;
    if (!apply[b]) return;             // wave-uniform; LUT never read for these
    const int tile = bt & 63;
    const int tyi = tile >> 3, txi = tile & 7;

    const int oy = offy[b], ox = offx[b];
    const int by = tyi * TILE, bx = txi * TILE;
    const int sy = vflip[b] ? (IH - TILE - oy - by) : (oy + by);
    const int sx = hflip[b] ? (IW - TILE - ox - bx) : (ox + bx);

    __shared__ unsigned int hist[4][NBINS];   // per-wave sub-histograms
    const int t    = threadIdx.x;
    const int lane = t & 63;
    const int wid  = t >> 6;
    #pragma unroll
    for (int w = 0; w < 4; ++w) hist[w][t] = 0u;
    __syncthreads();

    const float* __restrict__ xb = x + (size_t)b * (IH * IW);

    #pragma unroll
    for (int k = 0; k < 4; ++k) {
        const int q    = t + k * 256;
        const int row  = q >> 4;
        const int col4 = (q & 15) << 2;
        const fvec4 v = *reinterpret_cast<const fvec4*>(
                             xb + (size_t)(sy + row) * IW + sx + col4);
        #pragma unroll
        for (int j = 0; j < 4; ++j) {
            int bin = (int)(v[j] * 256.0f);
            bin = bin < 0 ? 0 : (bin > 255 ? 255 : bin);
            atomicAdd(&hist[wid][bin], 1u);
        }
    }
    __syncthreads();

    const float h = (float)(hist[0][t] + hist[1][t] + hist[2][t] + hist[3][t]);
    const float clipped = fminf(h, CLIPV);
    float ex = h - clipped;

    #pragma unroll
    for (int off = 32; off > 0; off >>= 1) ex += __shfl_down(ex, off, 64);
    __shared__ float wsum[4];
    if (lane == 0) wsum[wid] = ex;
    __syncthreads();
    const float excess = wsum[0] + wsum[1] + wsum[2] + wsum[3];

    const float hv = clipped + excess * (1.0f / (float)NBINS);

    float s = hv;
    #pragma unroll
    for (int off = 1; off < 64; off <<= 1) {
        const float n = __shfl_up(s, off, 64);
        if (lane >= off) s += n;
    }
    __shared__ float wtot[4];
    if (lane == 63) wtot[wid] = s;
    __syncthreads();
    float prefix = 0.0f;
    for (int w = 0; w < wid; ++w) prefix += wtot[w];
    s += prefix;

    float lut = s * (255.0f / (float)TP);
    lut = fminf(fmaxf(lut, 0.0f), 255.0f);
    luts[(size_t)bt * NBINS + t] = lut;
}

// ---------------------------------------------------------------------------
// Kernel 2: output. Block = 64-col x 16-row region of one image (aligned so
// the y-tile pair is constant per block and the x-tile pair is constant per
// 32-col half). Stage an interleaved quad-LUT lutq[half][bin]={v00,v01,v10,v11}
// in LDS -> ONE ds_read_b128 per pixel instead of 4 scattered L1 gathers.
// 8x32=256 blocks per image, 16384 total, 256 threads (thread = 4 px).
// ---------------------------------------------------------------------------
__global__ __launch_bounds__(256) void augment_out_kernel(
    const float* __restrict__ x,
    const int* __restrict__ hflip, const int* __restrict__ vflip,
    const int* __restrict__ offy,  const int* __restrict__ offx,
    const int* __restrict__ apply,
    const float* __restrict__ luts,
    float* __restrict__ out)
{
    const int bid = blockIdx.x;
    const int b   = bid >> 8;            // 256 blocks / image (scalar)
    const int blk = bid & 255;
    const int cb  = blk & 7;             // 64-wide col stripe index
    const int rb  = blk >> 3;            // 16-tall row stripe index

    const int t  = threadIdx.x;
    const int tc = t & 15;               // col group of 4 within stripe
    const int r  = t >> 4;               // row within stripe [0,16)

    const int y   = rb * 16 + r;
    const int col = cb * 64 + tc * 4;    // first of 4 output cols

    const int hf = hflip[b], vf = vflip[b];
    const int oy = offy[b],  ox = offx[b];
    const int ap = apply[b];

    const int iy = vf ? (IH - 1 - oy - y) : (oy + y);
    const float* __restrict__ row = x + (size_t)b * (IH * IW) + (size_t)iy * IW;

    fvec4 v;
    if (hf) {
        const fvec4 rr = *reinterpret_cast<const fvec4*>(row + (IW - 4 - ox - col));
        v = (fvec4){rr.w, rr.z, rr.y, rr.x};
    } else {
        v = *reinterpret_cast<const fvec4*>(row + ox + col);
    }

    fvec4 o;
    if (ap) {                            // block-uniform branch
        // y-tile pair: constant over an aligned 16-row stripe
        // (y0f boundaries at y = 32+64k, all multiples of 16)
        const int y0f = (int)floorf((rb * 16 + 0.5f) * (1.0f / TILE) - 0.5f);
        const int y0  = max(0, min(NGRID - 1, y0f));
        const int y1  = max(0, min(NGRID - 1, y0f + 1));

        __shared__ fvec4 lutq[2][NBINS];     // 8 KiB: {v00,v01,v10,v11} per bin
        const float* __restrict__ lb = luts + (size_t)b * (64 * NBINS);
        #pragma unroll
        for (int h = 0; h < 2; ++h) {
            const int xl = max(0, min(NGRID - 1, cb - 1 + h));
            const int xr = max(0, min(NGRID - 1, cb + h));
            fvec4 q;
            q.x = lb[((y0 << 3) + xl) * NBINS + t];
            q.y = lb[((y0 << 3) + xr) * NBINS + t];
            q.z = lb[((y1 << 3) + xl) * NBINS + t];
            q.w = lb[((y1 << 3) + xr) * NBINS + t];
            lutq[h][t] = q;
        }
        __syncthreads();

        const float fy = (y + 0.5f) * (1.0f / TILE) - 0.5f - (float)y0f;
        const int   h  = tc >> 3;            // which 32-col half (uniform per thread)
        const float x0ff = (float)(cb - 1 + h);

        #pragma unroll
        for (int j = 0; j < 4; ++j) {
            const float fx = (col + j + 0.5f) * (1.0f / TILE) - 0.5f - x0ff;
            int bin = (int)(v[j] * 256.0f);
            bin = bin < 0 ? 0 : (bin > 255 ? 255 : bin);
            const fvec4 q = lutq[h][bin];    // one ds_read_b128
            const float top = (1.0f - fx) * q.x + fx * q.y;
            const float bot = (1.0f - fx) * q.z + fx * q.w;
            o[j] = ((1.0f - fy) * top + fy * bot) * (1.0f / 255.0f);
        }
    } else {
        o = v;
    }

    const size_t oidx = (size_t)b * (CROPSZ * CROPSZ / 4) + (size_t)y * (CROPSZ / 4) + (col >> 2);
    __builtin_nontemporal_store(o, reinterpret_cast<fvec4*>(out) + oidx);
}

// ---------------------------------------------------------------------------
extern "C" void kernel_launch(void* const* d_in, const int* in_sizes, int n_in,
                              void* d_out, int out_size, void* d_ws, size_t ws_size,
                              hipStream_t stream) {
    const float* x     = (const float*)d_in[0];
    const int*   hflip = (const int*)d_in[1];
    const int*   vflip = (const int*)d_in[2];
    const int*   offy  = (const int*)d_in[3];
    const int*   offx  = (const int*)d_in[4];
    const int*   apply = (const int*)d_in[5];
    float*       out   = (float*)d_out;
    float*       luts  = (float*)d_ws;   // 64*64*256*4 B = 4 MiB

    hipLaunchKernelGGL(clahe_lut_kernel, dim3(64 * 64), dim3(256), 0, stream,
                       x, hflip, vflip, offy, offx, apply, luts);

    hipLaunchKernelGGL(augment_out_kernel, dim3(64 * 256), dim3(256), 0, stream,
                       x, hflip, vflip, offy, offx, apply, luts, out);
}

// Round 7
// 179.334 us; speedup vs baseline: 1.1494x; 1.0115x over previous
//
#include <hip/hip_runtime.h>

#define IH 640
#define IW 640
#define CROPSZ 512
#define NGRID 8
#define TILE 64          // CROPSZ / NGRID
#define NBINS 256
#define TP (TILE*TILE)   // 4096 pixels per tile
// clip_val = max(0.8 * 4096 / 256, 1.0) = 12.8
#define CLIPV 12.8f

typedef float fvec4 __attribute__((ext_vector_type(4)));

// ---------------------------------------------------------------------------
// Kernel 1: per-(batch,tile) histogram -> clip/redistribute -> cumsum LUT.
// Histogram is order-independent; flips map the tile onto a mirrored
// contiguous block in input space -> plain forward 64x64 block, vec4 loads.
// One 256-thread block per (batch,tile). 4096 blocks.
// ---------------------------------------------------------------------------
__global__ __launch_bounds__(256) void clahe_lut_kernel(
    const float* __restrict__ x,
    const int* __restrict__ hflip, const int* __restrict__ vflip,
    const int* __restrict__ offy,  const int* __restrict__ offx,
    const int* __restrict__ apply,
    float* __restrict__ luts)
{
    const int bt = blockIdx.x;         // b*64 + tile  (scalar)
    const int b  = bt >> 6;
    if (!apply[b]) return;             // wave-uniform; LUT never read for these
    const int tile = bt & 63;
    const int tyi = tile >> 3, txi = tile & 7;

    const int oy = offy[b], ox = offx[b];
    const int by = tyi * TILE, bx = txi * TILE;
    const int sy = vflip[b] ? (IH - TILE - oy - by) : (oy + by);
    const int sx = hflip[b] ? (IW - TILE - ox - bx) : (ox + bx);

    __shared__ unsigned int hist[4][NBINS];   // per-wave sub-histograms
    const int t    = threadIdx.x;
    const int lane = t & 63;
    const int wid  = t >> 6;
    #pragma unroll
    for (int w = 0; w < 4; ++w) hist[w][t] = 0u;
    __syncthreads();

    const float* __restrict__ xb = x + (size_t)b * (IH * IW);

    #pragma unroll
    for (int k = 0; k < 4; ++k) {
        const int q    = t + k * 256;
        const int row  = q >> 4;
        const int col4 = (q & 15) << 2;
        const fvec4 v = __builtin_nontemporal_load(
            reinterpret_cast<const fvec4*>(xb + (size_t)(sy + row) * IW + sx + col4));
        #pragma unroll
        for (int j = 0; j < 4; ++j) {
            int bin = (int)(v[j] * 256.0f);
            bin = bin < 0 ? 0 : (bin > 255 ? 255 : bin);
            atomicAdd(&hist[wid][bin], 1u);
        }
    }
    __syncthreads();

    const float h = (float)(hist[0][t] + hist[1][t] + hist[2][t] + hist[3][t]);
    const float clipped = fminf(h, CLIPV);
    float ex = h - clipped;

    #pragma unroll
    for (int off = 32; off > 0; off >>= 1) ex += __shfl_down(ex, off, 64);
    __shared__ float wsum[4];
    if (lane == 0) wsum[wid] = ex;
    __syncthreads();
    const float excess = wsum[0] + wsum[1] + wsum[2] + wsum[3];

    const float hv = clipped + excess * (1.0f / (float)NBINS);

    float s = hv;
    #pragma unroll
    for (int off = 1; off < 64; off <<= 1) {
        const float n = __shfl_up(s, off, 64);
        if (lane >= off) s += n;
    }
    __shared__ float wtot[4];
    if (lane == 63) wtot[wid] = s;
    __syncthreads();
    float prefix = 0.0f;
    for (int w = 0; w < wid; ++w) prefix += wtot[w];
    s += prefix;

    float lut = s * (255.0f / (float)TP);
    lut = fminf(fmaxf(lut, 0.0f), 255.0f);
    luts[(size_t)bt * NBINS + t] = lut;
}

// ---------------------------------------------------------------------------
// Kernel 2: output. Block = 64x64 region of one image (1024 threads, 4 px
// each). The region has exactly 2 y-halves x 2 x-halves of constant tile
// pairs -> 4 interleaved quad-LUTs {v00,v01,v10,v11} staged in 16 KiB LDS,
// ONE entry per thread (single pass), then one ds_read_b128 per pixel.
// 64 blocks per image, 4096 total.
// ---------------------------------------------------------------------------
__global__ __launch_bounds__(1024) void augment_out_kernel(
    const float* __restrict__ x,
    const int* __restrict__ hflip, const int* __restrict__ vflip,
    const int* __restrict__ offy,  const int* __restrict__ offx,
    const int* __restrict__ apply,
    const float* __restrict__ luts,
    float* __restrict__ out)
{
    const int bid  = blockIdx.x;
    const int b    = bid >> 6;           // 64 blocks / image (scalar)
    const int blk  = bid & 63;
    const int cbig = blk & 7;            // 64-wide col stripe
    const int rbig = blk >> 3;           // 64-tall row stripe

    const int t  = threadIdx.x;
    const int tc = t & 15;               // col group of 4 within stripe
    const int r  = t >> 4;               // row within stripe [0,64)

    const int y   = rbig * 64 + r;
    const int col = cbig * 64 + tc * 4;  // first of 4 output cols

    const int hf = hflip[b], vf = vflip[b];
    const int oy = offy[b],  ox = offx[b];
    const int ap = apply[b];

    const int iy = vf ? (IH - 1 - oy - y) : (oy + y);
    const float* __restrict__ row = x + (size_t)b * (IH * IW) + (size_t)iy * IW;

    fvec4 v;
    if (hf) {
        const fvec4 rr = __builtin_nontemporal_load(
            reinterpret_cast<const fvec4*>(row + (IW - 4 - ox - col)));
        v = (fvec4){rr.w, rr.z, rr.y, rr.x};
    } else {
        v = __builtin_nontemporal_load(
            reinterpret_cast<const fvec4*>(row + ox + col));
    }

    fvec4 o;
    if (ap) {                            // block-uniform branch
        __shared__ fvec4 lutq[4][NBINS]; // 16 KiB: tab = hy*2+hx

        // stage: one entry per thread (1024 = 4 tables * 256 bins)
        {
            const int tab = t >> 8;      // 0..3
            const int bin = t & 255;
            const int hy  = tab >> 1, hx = tab & 1;
            const int y0  = max(0, min(NGRID - 1, rbig - 1 + hy));
            const int y1  = max(0, min(NGRID - 1, rbig     + hy));
            const int x0  = max(0, min(NGRID - 1, cbig - 1 + hx));
            const int x1  = max(0, min(NGRID - 1, cbig     + hx));
            const float* __restrict__ lb = luts + (size_t)b * (64 * NBINS);
            fvec4 q;
            q.x = lb[((y0 << 3) + x0) * NBINS + bin];
            q.y = lb[((y0 << 3) + x1) * NBINS + bin];
            q.z = lb[((y1 << 3) + x0) * NBINS + bin];
            q.w = lb[((y1 << 3) + x1) * NBINS + bin];
            lutq[tab][bin] = q;
        }
        __syncthreads();

        const int hy  = r >> 5;          // wave-uniform
        const int hx  = tc >> 3;         // per-lane, uniform over j
        const int tab = hy * 2 + hx;
        const float fy = (y + 0.5f) * (1.0f / TILE) - 0.5f - (float)(rbig - 1 + hy);

        #pragma unroll
        for (int j = 0; j < 4; ++j) {
            const float fx = (col + j + 0.5f) * (1.0f / TILE) - 0.5f - (float)(cbig - 1 + hx);
            int bin = (int)(v[j] * 256.0f);
            bin = bin < 0 ? 0 : (bin > 255 ? 255 : bin);
            const fvec4 q = lutq[tab][bin];    // one ds_read_b128
            const float top = (1.0f - fx) * q.x + fx * q.y;
            const float bot = (1.0f - fx) * q.z + fx * q.w;
            o[j] = ((1.0f - fy) * top + fy * bot) * (1.0f / 255.0f);
        }
    } else {
        o = v;
    }

    const size_t oidx = (size_t)b * (CROPSZ * CROPSZ / 4) + (size_t)y * (CROPSZ / 4) + (col >> 2);
    __builtin_nontemporal_store(o, reinterpret_cast<fvec4*>(out) + oidx);
}

// ---------------------------------------------------------------------------
extern "C" void kernel_launch(void* const* d_in, const int* in_sizes, int n_in,
                              void* d_out, int out_size, void* d_ws, size_t ws_size,
                              hipStream_t stream) {
    const float* x     = (const float*)d_in[0];
    const int*   hflip = (const int*)d_in[1];
    const int*   vflip = (const int*)d_in[2];
    const int*   offy  = (const int*)d_in[3];
    const int*   offx  = (const int*)d_in[4];
    const int*   apply = (const int*)d_in[5];
    float*       out   = (float*)d_out;
    float*       luts  = (float*)d_ws;   // 64*64*256*4 B = 4 MiB

    hipLaunchKernelGGL(clahe_lut_kernel, dim3(64 * 64), dim3(256), 0, stream,
                       x, hflip, vflip, offy, offx, apply, luts);

    hipLaunchKernelGGL(augment_out_kernel, dim3(64 * 64), dim3(1024), 0, stream,
                       x, hflip, vflip, offy, offx, apply, luts, out);
}